// Round 13
// baseline (369.332 us; speedup 1.0000x reference)
//
#include <hip/hip_runtime.h>

// SchNet on MI355X — round 30: paired-edge u64 gather. Each lane fetched
// 4B/edge/stream (u32, 2bf16 of a 256B row over 64 lanes); now lanes 0-31
// read edge 2k's row and lanes 32-63 edge 2k+1's (8B/lane = G13 sweet
// spot): half the loads, half the dependent chain (16 edges per 8-slot
// batch), __shfl_xor(32) folds halves. NOT a nodes/wave restructure —
// block shape/LDS/GEMMs/coordagg byte-identical to round 12 (333.9us
// verified). Loads in flight 16->32 VGPR lands at the 64-VGPR bucket edge.
// Canary: VGPR 56-64 = pipeline held; <=48 = compiler serialized (parity).

#define NN 10000
#define EE 320000
#define HH 128
#define GG 50
#define NF 128
#define NL 6
#define TROWS 512
#define TPB (TROWS/32)  // table blocks per layer = 16
#define NB 128          // histogram blocks; EE/NB = 2500 edges each (fits u16)
#define PKW 1024        // LDS descriptor window per update block

typedef unsigned short u16;
typedef unsigned int u32;
typedef unsigned long long u64;
typedef short bf16x8 __attribute__((ext_vector_type(8)));
typedef float f32x4  __attribute__((ext_vector_type(4)));

__device__ __forceinline__ float us2f(u16 u){
  union { float f; u32 i; } v; v.i = ((u32)u) << 16; return v.f;
}
__device__ __forceinline__ u16 f2us(float x){
  union { float f; u32 i; } v; v.f = x;
  u32 r = v.i + 0x7fffu + ((v.i >> 16) & 1u);   // RNE
  return (u16)(r >> 16);
}
__device__ __forceinline__ float ldin(const void* p, int i, int bf){
  return bf ? us2f(((const u16*)p)[i]) : ((const float*)p)[i];
}
__device__ __forceinline__ float sspf(float x){
  return fmaxf(x, 0.f) + __logf(1.f + __expf(-fabsf(x))) - 0.6931472f;
}
__device__ __forceinline__ int detect_bf(const u32* __restrict__ zraw){
  int lane = threadIdx.x & 63;
  int c = 0;
  #pragma unroll
  for(int j=0;j<4;j++){
    u32 w = zraw[lane*4+j];
    u32 hb = (w >> 8) & 0x7F;
    c += (hb >= 0x38 && hb <= 0x41) ? 1 : 0;
  }
  return __popcll(__ballot(c >= 2)) >= 32;
}
__device__ __forceinline__ int detect_i64(const int* __restrict__ ei_raw){
  int lane = threadIdx.x & 63;
  int c = 0;
  #pragma unroll
  for(int j=0;j<4;j++) c += (ei_raw[2*(lane*4+j)+1] == 0) ? 1 : 0;
  return __popcll(__ballot(c >= 3)) >= 32;
}

// ---------- K1: fused init + weight prep ----------
__global__ void k_prep(const u32* __restrict__ zraw, const void* __restrict__ pos_in,
    const void* __restrict__ mlp1_w, const void* __restrict__ mlp1_b,
    const void* __restrict__ mlp2_w, const void* __restrict__ mlp2_b,
    const void* __restrict__ lin1_w, const void* __restrict__ lin2_w,
    const void* __restrict__ lin2_b, const void* __restrict__ lin_w,
    const void* __restrict__ lin_b,  const void* __restrict__ coord_w,
    const void* __restrict__ coord_b,
    float* __restrict__ h, float* __restrict__ pc40, int* __restrict__ wmaxi,
    float* __restrict__ b1f, float* __restrict__ b2v,
    u16* __restrict__ w1b, u16* __restrict__ w2bb,
    u16* __restrict__ l1b, u16* __restrict__ l2b,
    float* __restrict__ l2bf, u16* __restrict__ lwb,
    float* __restrict__ lbf, float* __restrict__ cwf, float* __restrict__ cbf)
{
  int bf = detect_bf(zraw);
  int b = blockIdx.x;
  if(b < NN*HH/256){
    int i = b*256 + threadIdx.x;
    h[i] = ldin(zraw, i, bf);
    if(i < NN*3){
      int n = i/3, comp = i%3;
      pc40[n*4 + comp] = ldin(pos_in, i, bf);
    }
    if(i == 0) *wmaxi = 0;
  } else {
    int i = (b - NN*HH/256)*256 + threadIdx.x;    // < NL*NF*NF
    if(i < NL*NF){
      b1f[i]  = ldin(mlp1_b, i, bf);
      b2v[i]  = ldin(mlp2_b, i, bf);
      l2bf[i] = ldin(lin2_b, i, bf);
      lbf[i]  = ldin(lin_b,  i, bf);
    }
    if(i < NL*NF*64){                             // w1b[l][f][g] bf16, K pad to 64
      int l = i/(NF*64), rem = i%(NF*64);
      int f = rem>>6, g = rem&63;
      w1b[i] = (g < GG) ? f2us(ldin(mlp1_w, (l*NF + f)*GG + g, bf)) : (u16)0;
    }
    if(i < NL*NF*NF){
      w2bb[i] = f2us(ldin(mlp2_w, i, bf));        // row-major bf16 (MFMA B)
      l1b[i]  = f2us(ldin(lin1_w, i, bf));
      l2b[i]  = f2us(ldin(lin2_w, i, bf));
      lwb[i]  = f2us(ldin(lin_w,  i, bf));
    }
    if(i < NL*(GG+2*HH)) cwf[i] = ldin(coord_w, i, bf);
    if(i < NL) cbf[i] = ldin(coord_b, i, bf);
  }
}

// ---------- K2: decode ei, distances (pc4 float4), LDS histograms ----------
__global__ void k_count(const int* __restrict__ ei_raw, const float* __restrict__ pc4,
                        int* __restrict__ eiN, float* __restrict__ wE,
                        u32* __restrict__ partR32, u32* __restrict__ partC32,
                        int* __restrict__ wmaxi){
  __shared__ u32 hr[NN/2];
  __shared__ u32 hc[NN/2];
  int is64 = detect_i64(ei_raw);
  int b = blockIdx.x, tid = threadIdx.x;          // grid: NB x 256
  for(int i=tid; i<NN/2; i+=256){ hr[i]=0; hc[i]=0; }
  __syncthreads();
  int e0 = b*(EE/NB), e1 = e0 + EE/NB;
  float wm = 0.f;
  for(int e = e0 + tid; e < e1; e += 256){
    int r = is64 ? ei_raw[2*e] : ei_raw[e];
    int c = is64 ? ei_raw[2*(EE+e)] : ei_raw[EE+e];
    eiN[e] = r; eiN[EE+e] = c;
    float4 pr = *(const float4*)&pc4[r*4];
    float4 pcv = *(const float4*)&pc4[c*4];
    float dx = pr.x-pcv.x, dy = pr.y-pcv.y, dz = pr.z-pcv.z;
    float w = sqrtf(dx*dx + dy*dy + dz*dz);
    wE[e] = w;
    wm = fmaxf(wm, w);
    atomicAdd(&hr[r>>1], (r&1) ? 0x10000u : 1u);
    atomicAdd(&hc[c>>1], (c&1) ? 0x10000u : 1u);
  }
  #pragma unroll
  for(int s=32; s>0; s>>=1) wm = fmaxf(wm, __shfl_down(wm, s, 64));
  if((tid & 63) == 0) atomicMax(wmaxi, __float_as_int(wm));
  __syncthreads();
  for(int i=tid; i<NN/2; i+=256){
    partR32[(size_t)b*(NN/2) + i] = hr[i];
    partC32[(size_t)b*(NN/2) + i] = hc[i];
  }
}

// ---------- K4: merged dual exclusive scan ----------
__global__ void k_scan2(const int* __restrict__ col_deg, const int* __restrict__ deg_row,
                        int* __restrict__ col_start, int* __restrict__ row_start){
  __shared__ int pc[1024];
  __shared__ int pr[1024];
  int tid = threadIdx.x;
  const int CH = (NN + 1023)/1024;
  int base = tid*CH;
  int sc = 0, sr = 0;
  for(int i=0;i<CH;i++){
    int idx = base+i;
    if(idx<NN){ sc += col_deg[idx]; sr += deg_row[idx]; }
  }
  pc[tid] = sc; pr[tid] = sr;
  __syncthreads();
  for(int off=1; off<1024; off<<=1){
    int vc = (tid>=off) ? pc[tid-off] : 0;
    int vr = (tid>=off) ? pr[tid-off] : 0;
    __syncthreads();
    pc[tid] += vc; pr[tid] += vr;
    __syncthreads();
  }
  int runc = (tid==0) ? 0 : pc[tid-1];
  int runr = (tid==0) ? 0 : pr[tid-1];
  for(int i=0;i<CH;i++){
    int idx = base+i;
    if(idx<NN){
      col_start[idx]=runc; runc += col_deg[idx];
      row_start[idx]=runr; runr += deg_row[idx];
    }
  }
  if(tid==1023){ col_start[NN] = runc; row_start[NN] = runr; }
}

// ---------- K5a: CSR fill via LDS rank histograms -> packed descriptors ----
__global__ void k_fill(const int* __restrict__ eiN, const float* __restrict__ wE,
                       const int* __restrict__ col_start, const int* __restrict__ row_start,
                       const u16* __restrict__ partR16, const u16* __restrict__ partC16,
                       const int* __restrict__ wmaxi,
                       u32* __restrict__ pk_s, u32* __restrict__ pkr_s){
  __shared__ u32 hr[NN/2];
  __shared__ u32 hc[NN/2];
  int b = blockIdx.x, t = threadIdx.x;
  for(int i=t; i<NN/2; i+=256){ hr[i]=0; hc[i]=0; }
  __syncthreads();
  float invD = (float)(TROWS-1) / __int_as_float(*wmaxi);
  int e0 = b*(EE/NB), e1 = e0 + EE/NB;
  for(int e = e0 + t; e < e1; e += 256){
    int r = eiN[e], c = eiN[EE+e];
    u32 i0 = (u32)min((int)(wE[e]*invD + 0.5f), TROWS-1);
    u32 oldc = atomicAdd(&hc[c>>1], (c&1) ? 0x10000u : 1u);
    u32 rkc = (c&1) ? (oldc >> 16) : (oldc & 0xFFFFu);
    int p = col_start[c] + (int)partC16[(size_t)b*NN + c] + (int)rkc;
    pk_s[p] = ((u32)r << 11) | i0;
    u32 oldr = atomicAdd(&hr[r>>1], (r&1) ? 0x10000u : 1u);
    u32 rkr = (r&1) ? (oldr >> 16) : (oldr & 0xFFFFu);
    int p2 = row_start[r] + (int)partR16[(size_t)b*NN + r] + (int)rkr;
    pkr_s[p2] = ((u32)c << 11) | i0;
  }
}

// ---------- K5b: MFMA table build + layer-0 xf/dots + sumpref (fused grid) ----
// blocks [0, NL*TPB)            : table, 32 rows each (bf16 MFMA GEMM pair)
// blocks [NL*TPB, +NN/16)       : layer-0 xf + coord dots (16 nodes each)
// blocks [.., +40)              : sumpref (independent of table/node)
__global__ void k_tabnode(const u16* __restrict__ w1b, const float* __restrict__ b1f,
                          const u16* __restrict__ w2bb, const float* __restrict__ b2v,
                          const float* __restrict__ cwf, const int* __restrict__ wmaxi,
                          u16* __restrict__ tabB, float* __restrict__ tabS,
                          const float* __restrict__ h, const u16* __restrict__ l1b,
                          u16* __restrict__ xfb0, float* __restrict__ dr0,
                          float* __restrict__ pc40,
                          u16* __restrict__ partR16, u16* __restrict__ partC16,
                          int* __restrict__ degR, int* __restrict__ degC){
  __shared__ __align__(16) u16 S[32*72 + 32*136];   // attr[32][72] | t1[32][136]
  int b = blockIdx.x, t = threadIdx.x;
  int wave = t >> 6, lane = t & 63;
  int m16 = lane & 15, quad = lane >> 4;
  if(b < NL*TPB){
    int l = b / TPB;
    int r0 = (b % TPB)*32;
    u16* attr = S;                 // [32][72] bf16, stride 72 (bank-shift 4/row)
    u16* t1   = S + 32*72;         // [32][136] bf16
    float delta = __int_as_float(*wmaxi) / (float)(TROWS-1);
    for(int idx=t; idx<32*64; idx+=256){
      int r = idx >> 6, g = idx & 63;
      float w = (float)(r0 + r)*delta;
      float d = w - (float)g*(10.f/49.f);
      attr[r*72 + g] = (g < GG) ? f2us(__expf(-12.005f*d*d)) : (u16)0;
    }
    __syncthreads();
    // ---- GEMM1: t1 = ssp(attr @ w1^T + b1)   M=32 N=128 K=64 ----
    {
      const u16* __restrict__ w1 = w1b + (size_t)l*NF*64;
      f32x4 acc[2][2];
      #pragma unroll
      for(int nc=0;nc<2;nc++){
        float bv = b1f[l*NF + wave*32 + nc*16 + m16];
        #pragma unroll
        for(int mr=0;mr<2;mr++) acc[mr][nc] = (f32x4){bv,bv,bv,bv};
      }
      #pragma unroll
      for(int ks=0; ks<2; ks++){
        bf16x8 aA[2], bB[2];
        #pragma unroll
        for(int mr=0;mr<2;mr++)
          aA[mr] = *(const bf16x8*)&attr[(mr*16 + m16)*72 + ks*32 + quad*8];
        #pragma unroll
        for(int nc=0;nc<2;nc++)
          bB[nc] = *(const bf16x8*)&w1[(wave*32 + nc*16 + m16)*64 + ks*32 + quad*8];
        #pragma unroll
        for(int mr=0;mr<2;mr++)
          #pragma unroll
          for(int nc=0;nc<2;nc++)
            acc[mr][nc] = __builtin_amdgcn_mfma_f32_16x16x32_bf16(aA[mr], bB[nc], acc[mr][nc], 0,0,0);
      }
      #pragma unroll
      for(int mr=0;mr<2;mr++)
        #pragma unroll
        for(int nc=0;nc<2;nc++)
          #pragma unroll
          for(int r=0;r<4;r++)
            t1[(mr*16 + quad*4 + r)*136 + wave*32 + nc*16 + m16] = f2us(sspf(acc[mr][nc][r]));
    }
    __syncthreads();
    // ---- GEMM2: tab = (t1 @ w2^T + b2) * C(row)   M=32 N=128 K=128 ----
    {
      const u16* __restrict__ w2 = w2bb + (size_t)l*NF*NF;
      f32x4 acc[2][2];
      #pragma unroll
      for(int nc=0;nc<2;nc++){
        float bv = b2v[l*NF + wave*32 + nc*16 + m16];
        #pragma unroll
        for(int mr=0;mr<2;mr++) acc[mr][nc] = (f32x4){bv,bv,bv,bv};
      }
      #pragma unroll
      for(int ks=0; ks<4; ks++){
        bf16x8 aA[2], bB[2];
        #pragma unroll
        for(int mr=0;mr<2;mr++)
          aA[mr] = *(const bf16x8*)&t1[(mr*16 + m16)*136 + ks*32 + quad*8];
        #pragma unroll
        for(int nc=0;nc<2;nc++)
          bB[nc] = *(const bf16x8*)&w2[(wave*32 + nc*16 + m16)*NF + ks*32 + quad*8];
        #pragma unroll
        for(int mr=0;mr<2;mr++)
          #pragma unroll
          for(int nc=0;nc<2;nc++)
            acc[mr][nc] = __builtin_amdgcn_mfma_f32_16x16x32_bf16(aA[mr], bB[nc], acc[mr][nc], 0,0,0);
      }
      #pragma unroll
      for(int mr=0;mr<2;mr++){
        #pragma unroll
        for(int r=0;r<4;r++){
          int row = r0 + mr*16 + quad*4 + r;
          float w = (float)row*delta;
          float C = 0.5f*(cosf(w*0.3141592653589793f) + 1.f);
          #pragma unroll
          for(int nc=0;nc<2;nc++)
            tabB[((size_t)l*TROWS + row)*NF + wave*32 + nc*16 + m16] = f2us(acc[mr][nc][r]*C);
        }
      }
    }
    // ---- tabS: f32 attr dot coord_w (32 threads, recompute exp in f32) ----
    if(t < 32){
      const float* __restrict__ cwg = cwf + l*(GG+2*HH);
      float w = (float)(r0 + t)*delta;
      float s = 0.f;
      for(int g=0; g<GG; g++){
        float d = w - (float)g*(10.f/49.f);
        s += __expf(-12.005f*d*d)*cwg[g];
      }
      tabS[l*TROWS + r0 + t] = s;
    }
  } else if(b < NL*TPB + NN/16){
    int n0 = (b - NL*TPB)*16;
    u16* T = S;                    // [16][136]
    // stage h rows f32 -> bf16 LDS
    {
      int node = t >> 4, c0 = (t & 15)*8;
      const float* hp = &h[(n0 + node)*HH + c0];
      f32x4 v0 = *(const f32x4*)hp;
      f32x4 v1 = *(const f32x4*)(hp+4);
      u16* d = &T[node*136 + c0];
      d[0]=f2us(v0[0]); d[1]=f2us(v0[1]); d[2]=f2us(v0[2]); d[3]=f2us(v0[3]);
      d[4]=f2us(v1[0]); d[5]=f2us(v1[1]); d[6]=f2us(v1[2]); d[7]=f2us(v1[3]);
    }
    __syncthreads();
    // coord dots (l=0): 16 threads per node
    {
      const float* __restrict__ cw = cwf;
      int j = t >> 4, l16 = t & 15;
      float ar = 0.f, ac = 0.f;
      #pragma unroll
      for(int i=0;i<8;i++){
        float hvv = us2f(T[j*136 + l16 + 16*i]);
        ar += hvv*cw[GG + l16 + 16*i];
        ac += hvv*cw[GG + HH + l16 + 16*i];
      }
      #pragma unroll
      for(int s=8; s>0; s>>=1){
        ar += __shfl_down(ar, s, 16);
        ac += __shfl_down(ac, s, 16);
      }
      if(l16 == 0){ dr0[n0+j] = ar; pc40[(n0+j)*4+3] = ac; }
    }
    // GEMM: xf0 = h @ lin1^T   M=16 N=128 K=128 (wave covers 32 cols)
    {
      const u16* __restrict__ wC = l1b;          // layer 0
      bf16x8 aH[4];
      #pragma unroll
      for(int ks=0; ks<4; ks++)
        aH[ks] = *(const bf16x8*)&T[m16*136 + ks*32 + quad*8];
      #pragma unroll
      for(int nc=0; nc<2; nc++){
        int fcol = wave*32 + nc*16 + m16;
        f32x4 acc = (f32x4){0.f,0.f,0.f,0.f};
        #pragma unroll
        for(int ks=0; ks<4; ks++){
          bf16x8 bbv = *(const bf16x8*)&wC[fcol*HH + ks*32 + quad*8];
          acc = __builtin_amdgcn_mfma_f32_16x16x32_bf16(aH[ks], bbv, acc, 0,0,0);
        }
        #pragma unroll
        for(int r=0;r<4;r++)
          xfb0[(n0+quad*4+r)*NF + fcol] = f2us(acc[r]);
      }
    }
  } else {
    // ---- sumpref: u16 partials -> exclusive block-prefixes + totals ----
    int n = (b - (NL*TPB + NN/16))*256 + t;
    if(n >= NN) return;
    u32 rr = 0, rc = 0;
    for(int b0=0; b0<NB; b0+=8){
      u32 vr[8], vc[8];
      #pragma unroll
      for(int j=0;j<8;j++){
        vr[j] = partR16[(size_t)(b0+j)*NN + n];
        vc[j] = partC16[(size_t)(b0+j)*NN + n];
      }
      #pragma unroll
      for(int j=0;j<8;j++){
        partR16[(size_t)(b0+j)*NN + n] = (u16)rr; rr += vr[j];
        partC16[(size_t)(b0+j)*NN + n] = (u16)rc; rc += vc[j];
      }
    }
    degR[n] = (int)rr; degC[n] = (int)rc;
  }
}

// ---------- per-layer fused kernel, interleaved block types ----------
// b%3==0 -> update unit b/3 (16 nodes): LDS-staged packed descriptors ->
// paired-edge u64 gather (16 edges/batch, halves fold via shfl_xor 32) ->
// LDS -> MFMA GEMM1/2/3 + dots. Else coordagg unit (8 nodes, pc4 loads).
__global__ void k_layer(const int* __restrict__ col_start, const u32* __restrict__ pk_s,
                        const u32* __restrict__ xfR, u16* __restrict__ xfW,
                        const u16* __restrict__ tabB, int l,
                        const u16* __restrict__ l2b, const float* __restrict__ l2bf,
                        const u16* __restrict__ lwb, const float* __restrict__ lbf,
                        float* __restrict__ h, const u16* __restrict__ l1b,
                        const float* __restrict__ cwf,
                        const float* __restrict__ drR, float* __restrict__ drW,
                        const int* __restrict__ row_start, const u32* __restrict__ pkr_s,
                        const float* __restrict__ tabS, const float* __restrict__ cbf,
                        const float* __restrict__ pc4R, float* __restrict__ pc4W,
                        const u32* __restrict__ zraw, void* __restrict__ out){
  __shared__ __align__(16) u16 T[16*136];
  __shared__ __align__(16) u16 T2[16*136];
  __shared__ u32 PK[PKW];
  int b = blockIdx.x, t = threadIdx.x;
  int wave = t >> 6, lane = t & 63;

  if(b % 3 == 0){
    int n0 = (b/3)*16;
    int base = col_start[n0];
    // ---- stage descriptors for the whole block (coalesced) ----
    {
      int cnt = min(col_start[n0+16] - base, PKW);
      for(int i = t; i < cnt; i += 512) PK[i] = pk_s[base + i];
    }
    __syncthreads();
    // ---- gather: paired-edge u64 loads, 8 slots = 16 edges per batch ----
    {
      const u64* __restrict__ tg64 = (const u64*)(tabB + (size_t)l*TROWS*NF);
      const u64* __restrict__ xf64 = (const u64*)xfR;
      u32* __restrict__ T32 = (u32*)T;
      int half = lane >> 5, ll = lane & 31;
      #pragma unroll
      for(int j=0;j<2;j++){
        int n = n0 + wave*2 + j;
        int p0 = col_start[n], p1 = col_start[n+1];
        float a0=0.f,a1=0.f,a2=0.f,a3=0.f;      // rotation set A (even slots)
        float c0=0.f,c1=0.f,c2=0.f,c3=0.f;      // rotation set B (odd slots)
        if(p1 - base <= PKW){
          int q = p0 - base, qe = p1 - base;
          for(; q+16 <= qe; q += 16){
            u32 pk[8]; u64 gv[8], xv[8];
            #pragma unroll
            for(int k=0;k<8;k++) pk[k] = PK[q + 2*k + half];
            #pragma unroll
            for(int k=0;k<8;k++){
              gv[k] = tg64[(pk[k] & 2047u)*32 + ll];
              xv[k] = xf64[(pk[k] >> 11)*32 + ll];
            }
            #pragma unroll
            for(int k=0;k<8;k++){
              u32 glo = (u32)gv[k], ghi = (u32)(gv[k]>>32);
              u32 xlo = (u32)xv[k], xhi = (u32)(xv[k]>>32);
              if(k & 1){
                c0 += us2f((u16)xlo)      * us2f((u16)glo);
                c1 += us2f((u16)(xlo>>16))* us2f((u16)(glo>>16));
                c2 += us2f((u16)xhi)      * us2f((u16)ghi);
                c3 += us2f((u16)(xhi>>16))* us2f((u16)(ghi>>16));
              } else {
                a0 += us2f((u16)xlo)      * us2f((u16)glo);
                a1 += us2f((u16)(xlo>>16))* us2f((u16)(glo>>16));
                a2 += us2f((u16)xhi)      * us2f((u16)ghi);
                a3 += us2f((u16)(xhi>>16))* us2f((u16)(ghi>>16));
              }
            }
          }
          for(; q < qe; q += 2){                 // tail: 2 edges, guard half 1
            int e = q + half;
            if(e < qe){
              u32 pk = PK[e];
              u64 gv = tg64[(pk & 2047u)*32 + ll];
              u64 xv = xf64[(pk >> 11)*32 + ll];
              u32 glo = (u32)gv, ghi = (u32)(gv>>32);
              u32 xlo = (u32)xv, xhi = (u32)(xv>>32);
              a0 += us2f((u16)xlo)      * us2f((u16)glo);
              a1 += us2f((u16)(xlo>>16))* us2f((u16)(glo>>16));
              a2 += us2f((u16)xhi)      * us2f((u16)ghi);
              a3 += us2f((u16)(xhi>>16))* us2f((u16)(ghi>>16));
            }
          }
        } else {
          for(int q = p0; q < p1; q += 2){       // rare fallback: global pk_s
            int e = q + half;
            if(e < p1){
              u32 pk = pk_s[e];
              u64 gv = tg64[(pk & 2047u)*32 + ll];
              u64 xv = xf64[(pk >> 11)*32 + ll];
              u32 glo = (u32)gv, ghi = (u32)(gv>>32);
              u32 xlo = (u32)xv, xhi = (u32)(xv>>32);
              a0 += us2f((u16)xlo)      * us2f((u16)glo);
              a1 += us2f((u16)(xlo>>16))* us2f((u16)(glo>>16));
              a2 += us2f((u16)xhi)      * us2f((u16)ghi);
              a3 += us2f((u16)(xhi>>16))* us2f((u16)(ghi>>16));
            }
          }
        }
        float t0 = a0 + c0, t1 = a1 + c1, t2 = a2 + c2, t3 = a3 + c3;
        t0 += __shfl_xor(t0, 32, 64);
        t1 += __shfl_xor(t1, 32, 64);
        t2 += __shfl_xor(t2, 32, 64);
        t3 += __shfl_xor(t3, 32, 64);
        if(half == 0){
          T32[(wave*2+j)*68 + 2*ll]     = (u32)f2us(t0) | ((u32)f2us(t1) << 16);
          T32[(wave*2+j)*68 + 2*ll + 1] = (u32)f2us(t2) | ((u32)f2us(t3) << 16);
        }
      }
    }
    __syncthreads();
    int m16 = lane & 15, quad = lane >> 4;
    int fcol = wave*16 + m16;
    f32x4 acc;
    // ---- GEMM1: sg = ssp(agg @ lin2^T + b) ----
    {
      bf16x8 aA[4];
      #pragma unroll
      for(int ks=0; ks<4; ks++)
        aA[ks] = *(const bf16x8*)&T[m16*136 + ks*32 + quad*8];
      const u16* __restrict__ wA = l2b + l*HH*NF;
      float bv = l2bf[l*HH + fcol];
      acc = (f32x4){bv,bv,bv,bv};
      #pragma unroll
      for(int ks=0; ks<4; ks++){
        bf16x8 bbv = *(const bf16x8*)&wA[fcol*NF + ks*32 + quad*8];
        acc = __builtin_amdgcn_mfma_f32_16x16x32_bf16(aA[ks], bbv, acc, 0,0,0);
      }
      #pragma unroll
      for(int r=0;r<4;r++)
        T2[(quad*4+r)*136 + fcol] = f2us(sspf(acc[r]));
    }
    __syncthreads();
    // ---- GEMM2: hv = h + sg @ lin^T + b  (h via non-temporal) ----
    float hv[4];
    int bf = (l == NL-1) ? detect_bf(zraw) : 0;
    {
      bf16x8 aS[4];
      #pragma unroll
      for(int ks=0; ks<4; ks++)
        aS[ks] = *(const bf16x8*)&T2[m16*136 + ks*32 + quad*8];
      const u16* __restrict__ wB = lwb + l*HH*HH;
      float bv = lbf[l*HH + fcol];
      acc = (f32x4){bv,bv,bv,bv};
      #pragma unroll
      for(int ks=0; ks<4; ks++){
        bf16x8 bbv = *(const bf16x8*)&wB[fcol*HH + ks*32 + quad*8];
        acc = __builtin_amdgcn_mfma_f32_16x16x32_bf16(aS[ks], bbv, acc, 0,0,0);
      }
      #pragma unroll
      for(int r=0;r<4;r++)
        hv[r] = __builtin_nontemporal_load(&h[(n0+quad*4+r)*HH + fcol]) + acc[r];
    }
    if(l == NL-1){
      #pragma unroll
      for(int r=0;r<4;r++){
        int n = n0 + quad*4 + r;
        if(bf) ((u16*)out)[NN*3 + n*HH + fcol] = f2us(hv[r]);
        else   ((float*)out)[NN*3 + n*HH + fcol] = hv[r];
      }
      return;
    }
    #pragma unroll
    for(int r=0;r<4;r++){
      int n = n0 + quad*4 + r;
      __builtin_nontemporal_store(hv[r], &h[n*HH + fcol]);
      T[(quad*4+r)*136 + fcol] = f2us(hv[r]);
    }
    __syncthreads();
    // ---- GEMM3: xf(l+1) = h_new @ lin1^T ----
    {
      bf16x8 aH[4];
      #pragma unroll
      for(int ks=0; ks<4; ks++)
        aH[ks] = *(const bf16x8*)&T[m16*136 + ks*32 + quad*8];
      const u16* __restrict__ wC = l1b + (l+1)*NF*HH;
      acc = (f32x4){0.f,0.f,0.f,0.f};
      #pragma unroll
      for(int ks=0; ks<4; ks++){
        bf16x8 bbv = *(const bf16x8*)&wC[fcol*HH + ks*32 + quad*8];
        acc = __builtin_amdgcn_mfma_f32_16x16x32_bf16(aH[ks], bbv, acc, 0,0,0);
      }
      #pragma unroll
      for(int r=0;r<4;r++)
        xfW[(n0+quad*4+r)*NF + fcol] = f2us(acc[r]);
    }
    // ---- coord dots(l+1) from h_new (32 threads/node) ----
    {
      const float* __restrict__ cw = cwf + (l+1)*(GG + 2*HH);
      int j = t >> 5, l32 = t & 31;
      float ar = 0.f, ac = 0.f;
      #pragma unroll
      for(int i=0;i<4;i++){
        float hvv = us2f(T[j*136 + l32 + 32*i]);
        ar += hvv*cw[GG + l32 + 32*i];
        ac += hvv*cw[GG + HH + l32 + 32*i];
      }
      #pragma unroll
      for(int s=16; s>0; s>>=1){
        ar += __shfl_down(ar, s, 32);
        ac += __shfl_down(ac, s, 32);
      }
      if(l32 == 0){ drW[n0+j] = ar; pc4W[(n0+j)*4+3] = ac; }
    }
  } else {
    // ---- coordagg: 8 nodes/unit (wave per node), packed descriptors ----
    int u = b - b/3 - 1;                          // 0..NN/8-1
    int bf = (l == NL-1) ? detect_bf(zraw) : 0;
    int n = u*8 + wave;
    const float* __restrict__ ts = tabS + l*TROWS;
    float cb = cbf[l] + drR[n];
    int p0 = row_start[n], p1 = row_start[n+1];
    float4 pn = *(const float4*)&pc4R[n*4];
    float sx=0.f, sy=0.f, sz=0.f;
    for(int p = p0 + lane; p < p1; p += 64){
      u32 pk = pkr_s[p];
      int c = (int)(pk >> 11);
      float4 pcv = *(const float4*)&pc4R[c*4];
      float a = cb + pcv.w + ts[pk & 2047u];
      sx += (pn.x - pcv.x)*a;
      sy += (pn.y - pcv.y)*a;
      sz += (pn.z - pcv.z)*a;
    }
    #pragma unroll
    for(int s=32; s>0; s>>=1){
      sx += __shfl_down(sx, s, 64);
      sy += __shfl_down(sy, s, 64);
      sz += __shfl_down(sz, s, 64);
    }
    if(lane == 0){
      int cnt = p1 - p0;
      float inv = (cnt > 0) ? 1.f/(float)cnt : 0.f;
      float ox = pn.x + sx*inv, oy = pn.y + sy*inv, oz = pn.z + sz*inv;
      if(l == NL-1){
        if(bf){
          u16* o = (u16*)out;
          o[n*3+0] = f2us(ox); o[n*3+1] = f2us(oy); o[n*3+2] = f2us(oz);
        } else {
          float* o = (float*)out;
          o[n*3+0] = ox; o[n*3+1] = oy; o[n*3+2] = oz;
        }
      } else {
        pc4W[n*4+0] = ox; pc4W[n*4+1] = oy; pc4W[n*4+2] = oz;
      }
    }
  }
}

extern "C" void kernel_launch(void* const* d_in, const int* in_sizes, int n_in,
                              void* d_out, int out_size, void* d_ws, size_t ws_size,
                              hipStream_t stream){
  const u32*  z      = (const u32*)d_in[0];
  const void* pos_in = d_in[1];
  const int*  ei_raw = (const int*)d_in[2];
  const void* mlp1_w = d_in[3];
  const void* mlp1_b = d_in[4];
  const void* mlp2_w = d_in[5];
  const void* mlp2_b = d_in[6];
  const void* lin1_w = d_in[7];
  const void* lin2_w = d_in[8];
  const void* lin2_b = d_in[9];
  const void* lin_w  = d_in[10];
  const void* lin_b  = d_in[11];
  const void* coord_w= d_in[12];
  const void* coord_b= d_in[13];

  float* W = (float*)d_ws;
  float* h    = W; W += NN*HH;
  float* pc40 = W; W += NN*4;
  float* pc41 = W; W += NN*4;
  float* dr0  = W; W += NN;
  float* dr1  = W; W += NN;
  float* wE   = W; W += EE;
  float* b1f  = W; W += NL*NF;
  float* b2v  = W; W += NL*NF;
  float* l2bf = W; W += NL*HH;
  float* lbf  = W; W += NL*HH;
  float* cwf  = W; W += NL*(GG+2*HH);
  float* cbf  = W; W += NL;
  W = (float*)(((uintptr_t)W + 63) & ~(uintptr_t)63);
  u16*  tabB = (u16*)W; W += (size_t)NL*TROWS*NF/2;   // bf16 nearest table
  float* tabS = W; W += NL*TROWS;
  u16* w1b  = (u16*)W; W += (NL*NF*64)/2;             // bf16 [l][f][64] (K-pad)
  u16* w2bb = (u16*)W; W += (NL*NF*NF)/2;
  u16* l1b  = (u16*)W; W += (NL*NF*NF)/2;
  u16* l2b  = (u16*)W; W += (NL*NF*NF)/2;
  u16* lwb  = (u16*)W; W += (NL*NF*NF)/2;
  u16* xfb0 = (u16*)W; W += (NN*NF)/2;
  u16* xfb1 = (u16*)W; W += (NN*NF)/2;
  u16* partR16 = (u16*)W; W += (size_t)NB*NN/2;
  u16* partC16 = (u16*)W; W += (size_t)NB*NN/2;
  int* degR      = (int*)W; W += NN;
  int* degC      = (int*)W; W += NN;
  int* col_start = (int*)W; W += NN+1;
  int* row_start = (int*)W; W += NN+1;
  u32* pk_s      = (u32*)W; W += EE;
  u32* pkr_s     = (u32*)W; W += EE;
  int* eiN       = (int*)W; W += 2*EE;
  int* wmaxi     = (int*)W; W += 1;

  k_prep<<<NN*HH/256 + NL*NF*NF/256, 256, 0, stream>>>(
      z, pos_in, mlp1_w, mlp1_b, mlp2_w, mlp2_b, lin1_w, lin2_w, lin2_b,
      lin_w, lin_b, coord_w, coord_b,
      h, pc40, wmaxi,
      b1f, b2v, w1b, w2bb, l1b, l2b, l2bf, lwb, lbf, cwf, cbf);
  k_count<<<NB, 256, 0, stream>>>(ei_raw, pc40, eiN, wE,
                                  (u32*)partR16, (u32*)partC16, wmaxi);
  k_tabnode<<<NL*TPB + NN/16 + (NN+255)/256, 256, 0, stream>>>(
      w1b, b1f, w2bb, b2v, cwf, wmaxi, tabB, tabS,
      h, l1b, xfb0, dr0, pc40,
      partR16, partC16, degR, degC);
  k_scan2<<<1, 1024, 0, stream>>>(degC, degR, col_start, row_start);
  k_fill<<<NB, 256, 0, stream>>>(eiN, wE, col_start, row_start,
                                 partR16, partC16, wmaxi, pk_s, pkr_s);

  for(int l=0; l<NL; l++){
    int par = l & 1;
    const u32* xfR = (const u32*)(par ? xfb1 : xfb0);
    u16* xfW = par ? xfb0 : xfb1;
    const float* drR = par ? dr1 : dr0;   float* drW = par ? dr0 : dr1;
    const float* p4R = par ? pc41 : pc40; float* p4W = par ? pc40 : pc41;
    k_layer<<<3*(NN/16), 512, 0, stream>>>(      // 1875 = 625 update + 1250 coord
        col_start, pk_s, xfR, xfW, tabB, l,
        l2b, l2bf, lwb, lbf, h, l1b, cwf,
        drR, drW,
        row_start, pkr_s, tabS, cbf, p4R, p4W, z, d_out);
  }
}

// Round 14
// 333.849 us; speedup vs baseline: 1.1063x; 1.1063x over previous
//
#include <hip/hip_runtime.h>

// SchNet on MI355X — round 31: RESTORE round-12 verified best (333.9us).
// Round-13's paired-edge u64 gather regressed +35us (5th failed gather
// restructure — live-load state exceeded the 64-VGPR bucket, compiler
// serialized; narrower per-row coalescing + shfl overhead). All lever
// classes now measured: structure/pipelining/prep-parallelism all regress;
// data-stream shrinks (MFMA tabnode, packed descriptors, LDS-PK staging,
// TROWS=512 + nontemporal h) are the wins that got 410.9 -> 333.9.

#define NN 10000
#define EE 320000
#define HH 128
#define GG 50
#define NF 128
#define NL 6
#define TROWS 512
#define TPB (TROWS/32)  // table blocks per layer = 16
#define NB 128          // histogram blocks; EE/NB = 2500 edges each (fits u16)
#define PKW 1024        // LDS descriptor window per update block

typedef unsigned short u16;
typedef unsigned int u32;
typedef short bf16x8 __attribute__((ext_vector_type(8)));
typedef float f32x4  __attribute__((ext_vector_type(4)));

__device__ __forceinline__ float us2f(u16 u){
  union { float f; u32 i; } v; v.i = ((u32)u) << 16; return v.f;
}
__device__ __forceinline__ u16 f2us(float x){
  union { float f; u32 i; } v; v.f = x;
  u32 r = v.i + 0x7fffu + ((v.i >> 16) & 1u);   // RNE
  return (u16)(r >> 16);
}
__device__ __forceinline__ float ldin(const void* p, int i, int bf){
  return bf ? us2f(((const u16*)p)[i]) : ((const float*)p)[i];
}
__device__ __forceinline__ float sspf(float x){
  return fmaxf(x, 0.f) + __logf(1.f + __expf(-fabsf(x))) - 0.6931472f;
}
__device__ __forceinline__ int detect_bf(const u32* __restrict__ zraw){
  int lane = threadIdx.x & 63;
  int c = 0;
  #pragma unroll
  for(int j=0;j<4;j++){
    u32 w = zraw[lane*4+j];
    u32 hb = (w >> 8) & 0x7F;
    c += (hb >= 0x38 && hb <= 0x41) ? 1 : 0;
  }
  return __popcll(__ballot(c >= 2)) >= 32;
}
__device__ __forceinline__ int detect_i64(const int* __restrict__ ei_raw){
  int lane = threadIdx.x & 63;
  int c = 0;
  #pragma unroll
  for(int j=0;j<4;j++) c += (ei_raw[2*(lane*4+j)+1] == 0) ? 1 : 0;
  return __popcll(__ballot(c >= 3)) >= 32;
}

// ---------- K1: fused init + weight prep ----------
__global__ void k_prep(const u32* __restrict__ zraw, const void* __restrict__ pos_in,
    const void* __restrict__ mlp1_w, const void* __restrict__ mlp1_b,
    const void* __restrict__ mlp2_w, const void* __restrict__ mlp2_b,
    const void* __restrict__ lin1_w, const void* __restrict__ lin2_w,
    const void* __restrict__ lin2_b, const void* __restrict__ lin_w,
    const void* __restrict__ lin_b,  const void* __restrict__ coord_w,
    const void* __restrict__ coord_b,
    float* __restrict__ h, float* __restrict__ pc40, int* __restrict__ wmaxi,
    float* __restrict__ b1f, float* __restrict__ b2v,
    u16* __restrict__ w1b, u16* __restrict__ w2bb,
    u16* __restrict__ l1b, u16* __restrict__ l2b,
    float* __restrict__ l2bf, u16* __restrict__ lwb,
    float* __restrict__ lbf, float* __restrict__ cwf, float* __restrict__ cbf)
{
  int bf = detect_bf(zraw);
  int b = blockIdx.x;
  if(b < NN*HH/256){
    int i = b*256 + threadIdx.x;
    h[i] = ldin(zraw, i, bf);
    if(i < NN*3){
      int n = i/3, comp = i%3;
      pc40[n*4 + comp] = ldin(pos_in, i, bf);
    }
    if(i == 0) *wmaxi = 0;
  } else {
    int i = (b - NN*HH/256)*256 + threadIdx.x;    // < NL*NF*NF
    if(i < NL*NF){
      b1f[i]  = ldin(mlp1_b, i, bf);
      b2v[i]  = ldin(mlp2_b, i, bf);
      l2bf[i] = ldin(lin2_b, i, bf);
      lbf[i]  = ldin(lin_b,  i, bf);
    }
    if(i < NL*NF*64){                             // w1b[l][f][g] bf16, K pad to 64
      int l = i/(NF*64), rem = i%(NF*64);
      int f = rem>>6, g = rem&63;
      w1b[i] = (g < GG) ? f2us(ldin(mlp1_w, (l*NF + f)*GG + g, bf)) : (u16)0;
    }
    if(i < NL*NF*NF){
      w2bb[i] = f2us(ldin(mlp2_w, i, bf));        // row-major bf16 (MFMA B)
      l1b[i]  = f2us(ldin(lin1_w, i, bf));
      l2b[i]  = f2us(ldin(lin2_w, i, bf));
      lwb[i]  = f2us(ldin(lin_w,  i, bf));
    }
    if(i < NL*(GG+2*HH)) cwf[i] = ldin(coord_w, i, bf);
    if(i < NL) cbf[i] = ldin(coord_b, i, bf);
  }
}

// ---------- K2: decode ei, distances (pc4 float4), LDS histograms ----------
__global__ void k_count(const int* __restrict__ ei_raw, const float* __restrict__ pc4,
                        int* __restrict__ eiN, float* __restrict__ wE,
                        u32* __restrict__ partR32, u32* __restrict__ partC32,
                        int* __restrict__ wmaxi){
  __shared__ u32 hr[NN/2];
  __shared__ u32 hc[NN/2];
  int is64 = detect_i64(ei_raw);
  int b = blockIdx.x, tid = threadIdx.x;          // grid: NB x 256
  for(int i=tid; i<NN/2; i+=256){ hr[i]=0; hc[i]=0; }
  __syncthreads();
  int e0 = b*(EE/NB), e1 = e0 + EE/NB;
  float wm = 0.f;
  for(int e = e0 + tid; e < e1; e += 256){
    int r = is64 ? ei_raw[2*e] : ei_raw[e];
    int c = is64 ? ei_raw[2*(EE+e)] : ei_raw[EE+e];
    eiN[e] = r; eiN[EE+e] = c;
    float4 pr = *(const float4*)&pc4[r*4];
    float4 pcv = *(const float4*)&pc4[c*4];
    float dx = pr.x-pcv.x, dy = pr.y-pcv.y, dz = pr.z-pcv.z;
    float w = sqrtf(dx*dx + dy*dy + dz*dz);
    wE[e] = w;
    wm = fmaxf(wm, w);
    atomicAdd(&hr[r>>1], (r&1) ? 0x10000u : 1u);
    atomicAdd(&hc[c>>1], (c&1) ? 0x10000u : 1u);
  }
  #pragma unroll
  for(int s=32; s>0; s>>=1) wm = fmaxf(wm, __shfl_down(wm, s, 64));
  if((tid & 63) == 0) atomicMax(wmaxi, __float_as_int(wm));
  __syncthreads();
  for(int i=tid; i<NN/2; i+=256){
    partR32[(size_t)b*(NN/2) + i] = hr[i];
    partC32[(size_t)b*(NN/2) + i] = hc[i];
  }
}

// ---------- K4: merged dual exclusive scan ----------
__global__ void k_scan2(const int* __restrict__ col_deg, const int* __restrict__ deg_row,
                        int* __restrict__ col_start, int* __restrict__ row_start){
  __shared__ int pc[1024];
  __shared__ int pr[1024];
  int tid = threadIdx.x;
  const int CH = (NN + 1023)/1024;
  int base = tid*CH;
  int sc = 0, sr = 0;
  for(int i=0;i<CH;i++){
    int idx = base+i;
    if(idx<NN){ sc += col_deg[idx]; sr += deg_row[idx]; }
  }
  pc[tid] = sc; pr[tid] = sr;
  __syncthreads();
  for(int off=1; off<1024; off<<=1){
    int vc = (tid>=off) ? pc[tid-off] : 0;
    int vr = (tid>=off) ? pr[tid-off] : 0;
    __syncthreads();
    pc[tid] += vc; pr[tid] += vr;
    __syncthreads();
  }
  int runc = (tid==0) ? 0 : pc[tid-1];
  int runr = (tid==0) ? 0 : pr[tid-1];
  for(int i=0;i<CH;i++){
    int idx = base+i;
    if(idx<NN){
      col_start[idx]=runc; runc += col_deg[idx];
      row_start[idx]=runr; runr += deg_row[idx];
    }
  }
  if(tid==1023){ col_start[NN] = runc; row_start[NN] = runr; }
}

// ---------- K5a: CSR fill via LDS rank histograms -> packed descriptors ----
__global__ void k_fill(const int* __restrict__ eiN, const float* __restrict__ wE,
                       const int* __restrict__ col_start, const int* __restrict__ row_start,
                       const u16* __restrict__ partR16, const u16* __restrict__ partC16,
                       const int* __restrict__ wmaxi,
                       u32* __restrict__ pk_s, u32* __restrict__ pkr_s){
  __shared__ u32 hr[NN/2];
  __shared__ u32 hc[NN/2];
  int b = blockIdx.x, t = threadIdx.x;
  for(int i=t; i<NN/2; i+=256){ hr[i]=0; hc[i]=0; }
  __syncthreads();
  float invD = (float)(TROWS-1) / __int_as_float(*wmaxi);
  int e0 = b*(EE/NB), e1 = e0 + EE/NB;
  for(int e = e0 + t; e < e1; e += 256){
    int r = eiN[e], c = eiN[EE+e];
    u32 i0 = (u32)min((int)(wE[e]*invD + 0.5f), TROWS-1);
    u32 oldc = atomicAdd(&hc[c>>1], (c&1) ? 0x10000u : 1u);
    u32 rkc = (c&1) ? (oldc >> 16) : (oldc & 0xFFFFu);
    int p = col_start[c] + (int)partC16[(size_t)b*NN + c] + (int)rkc;
    pk_s[p] = ((u32)r << 11) | i0;
    u32 oldr = atomicAdd(&hr[r>>1], (r&1) ? 0x10000u : 1u);
    u32 rkr = (r&1) ? (oldr >> 16) : (oldr & 0xFFFFu);
    int p2 = row_start[r] + (int)partR16[(size_t)b*NN + r] + (int)rkr;
    pkr_s[p2] = ((u32)c << 11) | i0;
  }
}

// ---------- K5b: MFMA table build + layer-0 xf/dots + sumpref (fused grid) ----
// blocks [0, NL*TPB)            : table, 32 rows each (bf16 MFMA GEMM pair)
// blocks [NL*TPB, +NN/16)       : layer-0 xf + coord dots (16 nodes each)
// blocks [.., +40)              : sumpref (independent of table/node)
__global__ void k_tabnode(const u16* __restrict__ w1b, const float* __restrict__ b1f,
                          const u16* __restrict__ w2bb, const float* __restrict__ b2v,
                          const float* __restrict__ cwf, const int* __restrict__ wmaxi,
                          u16* __restrict__ tabB, float* __restrict__ tabS,
                          const float* __restrict__ h, const u16* __restrict__ l1b,
                          u16* __restrict__ xfb0, float* __restrict__ dr0,
                          float* __restrict__ pc40,
                          u16* __restrict__ partR16, u16* __restrict__ partC16,
                          int* __restrict__ degR, int* __restrict__ degC){
  __shared__ __align__(16) u16 S[32*72 + 32*136];   // attr[32][72] | t1[32][136]
  int b = blockIdx.x, t = threadIdx.x;
  int wave = t >> 6, lane = t & 63;
  int m16 = lane & 15, quad = lane >> 4;
  if(b < NL*TPB){
    int l = b / TPB;
    int r0 = (b % TPB)*32;
    u16* attr = S;                 // [32][72] bf16, stride 72 (bank-shift 4/row)
    u16* t1   = S + 32*72;         // [32][136] bf16
    float delta = __int_as_float(*wmaxi) / (float)(TROWS-1);
    for(int idx=t; idx<32*64; idx+=256){
      int r = idx >> 6, g = idx & 63;
      float w = (float)(r0 + r)*delta;
      float d = w - (float)g*(10.f/49.f);
      attr[r*72 + g] = (g < GG) ? f2us(__expf(-12.005f*d*d)) : (u16)0;
    }
    __syncthreads();
    // ---- GEMM1: t1 = ssp(attr @ w1^T + b1)   M=32 N=128 K=64 ----
    {
      const u16* __restrict__ w1 = w1b + (size_t)l*NF*64;
      f32x4 acc[2][2];
      #pragma unroll
      for(int nc=0;nc<2;nc++){
        float bv = b1f[l*NF + wave*32 + nc*16 + m16];
        #pragma unroll
        for(int mr=0;mr<2;mr++) acc[mr][nc] = (f32x4){bv,bv,bv,bv};
      }
      #pragma unroll
      for(int ks=0; ks<2; ks++){
        bf16x8 aA[2], bB[2];
        #pragma unroll
        for(int mr=0;mr<2;mr++)
          aA[mr] = *(const bf16x8*)&attr[(mr*16 + m16)*72 + ks*32 + quad*8];
        #pragma unroll
        for(int nc=0;nc<2;nc++)
          bB[nc] = *(const bf16x8*)&w1[(wave*32 + nc*16 + m16)*64 + ks*32 + quad*8];
        #pragma unroll
        for(int mr=0;mr<2;mr++)
          #pragma unroll
          for(int nc=0;nc<2;nc++)
            acc[mr][nc] = __builtin_amdgcn_mfma_f32_16x16x32_bf16(aA[mr], bB[nc], acc[mr][nc], 0,0,0);
      }
      #pragma unroll
      for(int mr=0;mr<2;mr++)
        #pragma unroll
        for(int nc=0;nc<2;nc++)
          #pragma unroll
          for(int r=0;r<4;r++)
            t1[(mr*16 + quad*4 + r)*136 + wave*32 + nc*16 + m16] = f2us(sspf(acc[mr][nc][r]));
    }
    __syncthreads();
    // ---- GEMM2: tab = (t1 @ w2^T + b2) * C(row)   M=32 N=128 K=128 ----
    {
      const u16* __restrict__ w2 = w2bb + (size_t)l*NF*NF;
      f32x4 acc[2][2];
      #pragma unroll
      for(int nc=0;nc<2;nc++){
        float bv = b2v[l*NF + wave*32 + nc*16 + m16];
        #pragma unroll
        for(int mr=0;mr<2;mr++) acc[mr][nc] = (f32x4){bv,bv,bv,bv};
      }
      #pragma unroll
      for(int ks=0; ks<4; ks++){
        bf16x8 aA[2], bB[2];
        #pragma unroll
        for(int mr=0;mr<2;mr++)
          aA[mr] = *(const bf16x8*)&t1[(mr*16 + m16)*136 + ks*32 + quad*8];
        #pragma unroll
        for(int nc=0;nc<2;nc++)
          bB[nc] = *(const bf16x8*)&w2[(wave*32 + nc*16 + m16)*NF + ks*32 + quad*8];
        #pragma unroll
        for(int mr=0;mr<2;mr++)
          #pragma unroll
          for(int nc=0;nc<2;nc++)
            acc[mr][nc] = __builtin_amdgcn_mfma_f32_16x16x32_bf16(aA[mr], bB[nc], acc[mr][nc], 0,0,0);
      }
      #pragma unroll
      for(int mr=0;mr<2;mr++){
        #pragma unroll
        for(int r=0;r<4;r++){
          int row = r0 + mr*16 + quad*4 + r;
          float w = (float)row*delta;
          float C = 0.5f*(cosf(w*0.3141592653589793f) + 1.f);
          #pragma unroll
          for(int nc=0;nc<2;nc++)
            tabB[((size_t)l*TROWS + row)*NF + wave*32 + nc*16 + m16] = f2us(acc[mr][nc][r]*C);
        }
      }
    }
    // ---- tabS: f32 attr dot coord_w (32 threads, recompute exp in f32) ----
    if(t < 32){
      const float* __restrict__ cwg = cwf + l*(GG+2*HH);
      float w = (float)(r0 + t)*delta;
      float s = 0.f;
      for(int g=0; g<GG; g++){
        float d = w - (float)g*(10.f/49.f);
        s += __expf(-12.005f*d*d)*cwg[g];
      }
      tabS[l*TROWS + r0 + t] = s;
    }
  } else if(b < NL*TPB + NN/16){
    int n0 = (b - NL*TPB)*16;
    u16* T = S;                    // [16][136]
    // stage h rows f32 -> bf16 LDS
    {
      int node = t >> 4, c0 = (t & 15)*8;
      const float* hp = &h[(n0 + node)*HH + c0];
      f32x4 v0 = *(const f32x4*)hp;
      f32x4 v1 = *(const f32x4*)(hp+4);
      u16* d = &T[node*136 + c0];
      d[0]=f2us(v0[0]); d[1]=f2us(v0[1]); d[2]=f2us(v0[2]); d[3]=f2us(v0[3]);
      d[4]=f2us(v1[0]); d[5]=f2us(v1[1]); d[6]=f2us(v1[2]); d[7]=f2us(v1[3]);
    }
    __syncthreads();
    // coord dots (l=0): 16 threads per node
    {
      const float* __restrict__ cw = cwf;
      int j = t >> 4, l16 = t & 15;
      float ar = 0.f, ac = 0.f;
      #pragma unroll
      for(int i=0;i<8;i++){
        float hvv = us2f(T[j*136 + l16 + 16*i]);
        ar += hvv*cw[GG + l16 + 16*i];
        ac += hvv*cw[GG + HH + l16 + 16*i];
      }
      #pragma unroll
      for(int s=8; s>0; s>>=1){
        ar += __shfl_down(ar, s, 16);
        ac += __shfl_down(ac, s, 16);
      }
      if(l16 == 0){ dr0[n0+j] = ar; pc40[(n0+j)*4+3] = ac; }
    }
    // GEMM: xf0 = h @ lin1^T   M=16 N=128 K=128 (wave covers 32 cols)
    {
      const u16* __restrict__ wC = l1b;          // layer 0
      bf16x8 aH[4];
      #pragma unroll
      for(int ks=0; ks<4; ks++)
        aH[ks] = *(const bf16x8*)&T[m16*136 + ks*32 + quad*8];
      #pragma unroll
      for(int nc=0; nc<2; nc++){
        int fcol = wave*32 + nc*16 + m16;
        f32x4 acc = (f32x4){0.f,0.f,0.f,0.f};
        #pragma unroll
        for(int ks=0; ks<4; ks++){
          bf16x8 bbv = *(const bf16x8*)&wC[fcol*HH + ks*32 + quad*8];
          acc = __builtin_amdgcn_mfma_f32_16x16x32_bf16(aH[ks], bbv, acc, 0,0,0);
        }
        #pragma unroll
        for(int r=0;r<4;r++)
          xfb0[(n0+quad*4+r)*NF + fcol] = f2us(acc[r]);
      }
    }
  } else {
    // ---- sumpref: u16 partials -> exclusive block-prefixes + totals ----
    int n = (b - (NL*TPB + NN/16))*256 + t;
    if(n >= NN) return;
    u32 rr = 0, rc = 0;
    for(int b0=0; b0<NB; b0+=8){
      u32 vr[8], vc[8];
      #pragma unroll
      for(int j=0;j<8;j++){
        vr[j] = partR16[(size_t)(b0+j)*NN + n];
        vc[j] = partC16[(size_t)(b0+j)*NN + n];
      }
      #pragma unroll
      for(int j=0;j<8;j++){
        partR16[(size_t)(b0+j)*NN + n] = (u16)rr; rr += vr[j];
        partC16[(size_t)(b0+j)*NN + n] = (u16)rc; rc += vc[j];
      }
    }
    degR[n] = (int)rr; degC[n] = (int)rc;
  }
}

// ---------- per-layer fused kernel, interleaved block types ----------
// b%3==0 -> update unit b/3 (16 nodes): LDS-staged packed descriptors ->
// table gather (unroll 8) -> LDS -> MFMA GEMM1/2/3 + dots. Else coordagg
// unit (8 nodes, pc4 loads). Parity ping-pong on xf/dr/pc4.
__global__ void k_layer(const int* __restrict__ col_start, const u32* __restrict__ pk_s,
                        const u32* __restrict__ xfR, u16* __restrict__ xfW,
                        const u16* __restrict__ tabB, int l,
                        const u16* __restrict__ l2b, const float* __restrict__ l2bf,
                        const u16* __restrict__ lwb, const float* __restrict__ lbf,
                        float* __restrict__ h, const u16* __restrict__ l1b,
                        const float* __restrict__ cwf,
                        const float* __restrict__ drR, float* __restrict__ drW,
                        const int* __restrict__ row_start, const u32* __restrict__ pkr_s,
                        const float* __restrict__ tabS, const float* __restrict__ cbf,
                        const float* __restrict__ pc4R, float* __restrict__ pc4W,
                        const u32* __restrict__ zraw, void* __restrict__ out){
  __shared__ __align__(16) u16 T[16*136];
  __shared__ __align__(16) u16 T2[16*136];
  __shared__ u32 PK[PKW];
  int b = blockIdx.x, t = threadIdx.x;
  int wave = t >> 6, lane = t & 63;

  if(b % 3 == 0){
    int n0 = (b/3)*16;
    int base = col_start[n0];
    // ---- stage descriptors for the whole block (coalesced) ----
    {
      int cnt = min(col_start[n0+16] - base, PKW);
      for(int i = t; i < cnt; i += 512) PK[i] = pk_s[base + i];
    }
    __syncthreads();
    // ---- gather: LDS descriptors, 8-edge unroll, 4 accumulator pairs ----
    {
      const u32* __restrict__ tg32 = (const u32*)(tabB + (size_t)l*TROWS*NF);
      u32* __restrict__ T32 = (u32*)T;
      #pragma unroll
      for(int j=0;j<2;j++){
        int n = n0 + wave*2 + j;
        int p0 = col_start[n], p1 = col_start[n+1];
        float aa[4] = {0.f,0.f,0.f,0.f};
        float bb[4] = {0.f,0.f,0.f,0.f};
        if(p1 - base <= PKW){
          int q = p0 - base, qe = p1 - base;
          for(; q+8 <= qe; q += 8){
            u32 pk[8], gv[8], xv[8];
            #pragma unroll
            for(int k=0;k<8;k++) pk[k] = PK[q+k];     // LDS broadcast read
            #pragma unroll
            for(int k=0;k<8;k++){
              gv[k] = tg32[(pk[k] & 2047u)*64 + lane];
              xv[k] = xfR[(pk[k] >> 11)*64 + lane];
            }
            #pragma unroll
            for(int k=0;k<8;k++){
              aa[k&3] += us2f((u16)xv[k])      * us2f((u16)gv[k]);
              bb[k&3] += us2f((u16)(xv[k]>>16))* us2f((u16)(gv[k]>>16));
            }
          }
          for(; q < qe; q++){
            u32 pk = PK[q];
            u32 g = tg32[(pk & 2047u)*64 + lane];
            u32 x = xfR[(pk >> 11)*64 + lane];
            aa[0] += us2f((u16)x)      * us2f((u16)g);
            bb[0] += us2f((u16)(x>>16))* us2f((u16)(g>>16));
          }
        } else {
          int p = p0;
          for(; p+8 <= p1; p += 8){
            u32 pk[8], gv[8], xv[8];
            #pragma unroll
            for(int k=0;k<8;k++) pk[k] = pk_s[p+k];
            #pragma unroll
            for(int k=0;k<8;k++){
              gv[k] = tg32[(pk[k] & 2047u)*64 + lane];
              xv[k] = xfR[(pk[k] >> 11)*64 + lane];
            }
            #pragma unroll
            for(int k=0;k<8;k++){
              aa[k&3] += us2f((u16)xv[k])      * us2f((u16)gv[k]);
              bb[k&3] += us2f((u16)(xv[k]>>16))* us2f((u16)(gv[k]>>16));
            }
          }
          for(; p < p1; p++){
            u32 pk = pk_s[p];
            u32 g = tg32[(pk & 2047u)*64 + lane];
            u32 x = xfR[(pk >> 11)*64 + lane];
            aa[0] += us2f((u16)x)      * us2f((u16)g);
            bb[0] += us2f((u16)(x>>16))* us2f((u16)(g>>16));
          }
        }
        float av = (aa[0]+aa[1])+(aa[2]+aa[3]);
        float bv = (bb[0]+bb[1])+(bb[2]+bb[3]);
        T32[(wave*2+j)*68 + lane] = (u32)f2us(av) | ((u32)f2us(bv) << 16);
      }
    }
    __syncthreads();
    int m16 = lane & 15, quad = lane >> 4;
    int fcol = wave*16 + m16;
    f32x4 acc;
    // ---- GEMM1: sg = ssp(agg @ lin2^T + b) ----
    {
      bf16x8 aA[4];
      #pragma unroll
      for(int ks=0; ks<4; ks++)
        aA[ks] = *(const bf16x8*)&T[m16*136 + ks*32 + quad*8];
      const u16* __restrict__ wA = l2b + l*HH*NF;
      float bv = l2bf[l*HH + fcol];
      acc = (f32x4){bv,bv,bv,bv};
      #pragma unroll
      for(int ks=0; ks<4; ks++){
        bf16x8 bbv = *(const bf16x8*)&wA[fcol*NF + ks*32 + quad*8];
        acc = __builtin_amdgcn_mfma_f32_16x16x32_bf16(aA[ks], bbv, acc, 0,0,0);
      }
      #pragma unroll
      for(int r=0;r<4;r++)
        T2[(quad*4+r)*136 + fcol] = f2us(sspf(acc[r]));
    }
    __syncthreads();
    // ---- GEMM2: hv = h + sg @ lin^T + b  (h via non-temporal) ----
    float hv[4];
    int bf = (l == NL-1) ? detect_bf(zraw) : 0;
    {
      bf16x8 aS[4];
      #pragma unroll
      for(int ks=0; ks<4; ks++)
        aS[ks] = *(const bf16x8*)&T2[m16*136 + ks*32 + quad*8];
      const u16* __restrict__ wB = lwb + l*HH*HH;
      float bv = lbf[l*HH + fcol];
      acc = (f32x4){bv,bv,bv,bv};
      #pragma unroll
      for(int ks=0; ks<4; ks++){
        bf16x8 bbv = *(const bf16x8*)&wB[fcol*HH + ks*32 + quad*8];
        acc = __builtin_amdgcn_mfma_f32_16x16x32_bf16(aS[ks], bbv, acc, 0,0,0);
      }
      #pragma unroll
      for(int r=0;r<4;r++)
        hv[r] = __builtin_nontemporal_load(&h[(n0+quad*4+r)*HH + fcol]) + acc[r];
    }
    if(l == NL-1){
      #pragma unroll
      for(int r=0;r<4;r++){
        int n = n0 + quad*4 + r;
        if(bf) ((u16*)out)[NN*3 + n*HH + fcol] = f2us(hv[r]);
        else   ((float*)out)[NN*3 + n*HH + fcol] = hv[r];
      }
      return;
    }
    #pragma unroll
    for(int r=0;r<4;r++){
      int n = n0 + quad*4 + r;
      __builtin_nontemporal_store(hv[r], &h[n*HH + fcol]);
      T[(quad*4+r)*136 + fcol] = f2us(hv[r]);
    }
    __syncthreads();
    // ---- GEMM3: xf(l+1) = h_new @ lin1^T ----
    {
      bf16x8 aH[4];
      #pragma unroll
      for(int ks=0; ks<4; ks++)
        aH[ks] = *(const bf16x8*)&T[m16*136 + ks*32 + quad*8];
      const u16* __restrict__ wC = l1b + (l+1)*NF*HH;
      acc = (f32x4){0.f,0.f,0.f,0.f};
      #pragma unroll
      for(int ks=0; ks<4; ks++){
        bf16x8 bbv = *(const bf16x8*)&wC[fcol*HH + ks*32 + quad*8];
        acc = __builtin_amdgcn_mfma_f32_16x16x32_bf16(aH[ks], bbv, acc, 0,0,0);
      }
      #pragma unroll
      for(int r=0;r<4;r++)
        xfW[(n0+quad*4+r)*NF + fcol] = f2us(acc[r]);
    }
    // ---- coord dots(l+1) from h_new (32 threads/node) ----
    {
      const float* __restrict__ cw = cwf + (l+1)*(GG + 2*HH);
      int j = t >> 5, l32 = t & 31;
      float ar = 0.f, ac = 0.f;
      #pragma unroll
      for(int i=0;i<4;i++){
        float hvv = us2f(T[j*136 + l32 + 32*i]);
        ar += hvv*cw[GG + l32 + 32*i];
        ac += hvv*cw[GG + HH + l32 + 32*i];
      }
      #pragma unroll
      for(int s=16; s>0; s>>=1){
        ar += __shfl_down(ar, s, 32);
        ac += __shfl_down(ac, s, 32);
      }
      if(l32 == 0){ drW[n0+j] = ar; pc4W[(n0+j)*4+3] = ac; }
    }
  } else {
    // ---- coordagg: 8 nodes/unit (wave per node), packed descriptors ----
    int u = b - b/3 - 1;                          // 0..NN/8-1
    int bf = (l == NL-1) ? detect_bf(zraw) : 0;
    int n = u*8 + wave;
    const float* __restrict__ ts = tabS + l*TROWS;
    float cb = cbf[l] + drR[n];
    int p0 = row_start[n], p1 = row_start[n+1];
    float4 pn = *(const float4*)&pc4R[n*4];
    float sx=0.f, sy=0.f, sz=0.f;
    for(int p = p0 + lane; p < p1; p += 64){
      u32 pk = pkr_s[p];
      int c = (int)(pk >> 11);
      float4 pcv = *(const float4*)&pc4R[c*4];
      float a = cb + pcv.w + ts[pk & 2047u];
      sx += (pn.x - pcv.x)*a;
      sy += (pn.y - pcv.y)*a;
      sz += (pn.z - pcv.z)*a;
    }
    #pragma unroll
    for(int s=32; s>0; s>>=1){
      sx += __shfl_down(sx, s, 64);
      sy += __shfl_down(sy, s, 64);
      sz += __shfl_down(sz, s, 64);
    }
    if(lane == 0){
      int cnt = p1 - p0;
      float inv = (cnt > 0) ? 1.f/(float)cnt : 0.f;
      float ox = pn.x + sx*inv, oy = pn.y + sy*inv, oz = pn.z + sz*inv;
      if(l == NL-1){
        if(bf){
          u16* o = (u16*)out;
          o[n*3+0] = f2us(ox); o[n*3+1] = f2us(oy); o[n*3+2] = f2us(oz);
        } else {
          float* o = (float*)out;
          o[n*3+0] = ox; o[n*3+1] = oy; o[n*3+2] = oz;
        }
      } else {
        pc4W[n*4+0] = ox; pc4W[n*4+1] = oy; pc4W[n*4+2] = oz;
      }
    }
  }
}

extern "C" void kernel_launch(void* const* d_in, const int* in_sizes, int n_in,
                              void* d_out, int out_size, void* d_ws, size_t ws_size,
                              hipStream_t stream){
  const u32*  z      = (const u32*)d_in[0];
  const void* pos_in = d_in[1];
  const int*  ei_raw = (const int*)d_in[2];
  const void* mlp1_w = d_in[3];
  const void* mlp1_b = d_in[4];
  const void* mlp2_w = d_in[5];
  const void* mlp2_b = d_in[6];
  const void* lin1_w = d_in[7];
  const void* lin2_w = d_in[8];
  const void* lin2_b = d_in[9];
  const void* lin_w  = d_in[10];
  const void* lin_b  = d_in[11];
  const void* coord_w= d_in[12];
  const void* coord_b= d_in[13];

  float* W = (float*)d_ws;
  float* h    = W; W += NN*HH;
  float* pc40 = W; W += NN*4;
  float* pc41 = W; W += NN*4;
  float* dr0  = W; W += NN;
  float* dr1  = W; W += NN;
  float* wE   = W; W += EE;
  float* b1f  = W; W += NL*NF;
  float* b2v  = W; W += NL*NF;
  float* l2bf = W; W += NL*HH;
  float* lbf  = W; W += NL*HH;
  float* cwf  = W; W += NL*(GG+2*HH);
  float* cbf  = W; W += NL;
  W = (float*)(((uintptr_t)W + 63) & ~(uintptr_t)63);
  u16*  tabB = (u16*)W; W += (size_t)NL*TROWS*NF/2;   // bf16 nearest table
  float* tabS = W; W += NL*TROWS;
  u16* w1b  = (u16*)W; W += (NL*NF*64)/2;             // bf16 [l][f][64] (K-pad)
  u16* w2bb = (u16*)W; W += (NL*NF*NF)/2;
  u16* l1b  = (u16*)W; W += (NL*NF*NF)/2;
  u16* l2b  = (u16*)W; W += (NL*NF*NF)/2;
  u16* lwb  = (u16*)W; W += (NL*NF*NF)/2;
  u16* xfb0 = (u16*)W; W += (NN*NF)/2;
  u16* xfb1 = (u16*)W; W += (NN*NF)/2;
  u16* partR16 = (u16*)W; W += (size_t)NB*NN/2;
  u16* partC16 = (u16*)W; W += (size_t)NB*NN/2;
  int* degR      = (int*)W; W += NN;
  int* degC      = (int*)W; W += NN;
  int* col_start = (int*)W; W += NN+1;
  int* row_start = (int*)W; W += NN+1;
  u32* pk_s      = (u32*)W; W += EE;
  u32* pkr_s     = (u32*)W; W += EE;
  int* eiN       = (int*)W; W += 2*EE;
  int* wmaxi     = (int*)W; W += 1;

  k_prep<<<NN*HH/256 + NL*NF*NF/256, 256, 0, stream>>>(
      z, pos_in, mlp1_w, mlp1_b, mlp2_w, mlp2_b, lin1_w, lin2_w, lin2_b,
      lin_w, lin_b, coord_w, coord_b,
      h, pc40, wmaxi,
      b1f, b2v, w1b, w2bb, l1b, l2b, l2bf, lwb, lbf, cwf, cbf);
  k_count<<<NB, 256, 0, stream>>>(ei_raw, pc40, eiN, wE,
                                  (u32*)partR16, (u32*)partC16, wmaxi);
  k_tabnode<<<NL*TPB + NN/16 + (NN+255)/256, 256, 0, stream>>>(
      w1b, b1f, w2bb, b2v, cwf, wmaxi, tabB, tabS,
      h, l1b, xfb0, dr0, pc40,
      partR16, partC16, degR, degC);
  k_scan2<<<1, 1024, 0, stream>>>(degC, degR, col_start, row_start);
  k_fill<<<NB, 256, 0, stream>>>(eiN, wE, col_start, row_start,
                                 partR16, partC16, wmaxi, pk_s, pkr_s);

  for(int l=0; l<NL; l++){
    int par = l & 1;
    const u32* xfR = (const u32*)(par ? xfb1 : xfb0);
    u16* xfW = par ? xfb0 : xfb1;
    const float* drR = par ? dr1 : dr0;   float* drW = par ? dr0 : dr1;
    const float* p4R = par ? pc41 : pc40; float* p4W = par ? pc40 : pc41;
    k_layer<<<3*(NN/16), 512, 0, stream>>>(      // 1875 = 625 update + 1250 coord
        col_start, pk_s, xfR, xfW, tabB, l,
        l2b, l2bf, lwb, lbf, h, l1b, cwf,
        drR, drW,
        row_start, pkr_s, tabS, cbf, p4R, p4W, z, d_out);
  }
}